// Round 6
// baseline (522.369 us; speedup 1.0000x reference)
//
#include <hip/hip_runtime.h>
#include <hip/hip_bf16.h>

#define N_NODES 8192
#define D_DIM   256

typedef __attribute__((ext_vector_type(8))) short short8v;   // 8 x bf16 (4 VGPR)
typedef __attribute__((ext_vector_type(4))) float f32x4;

__device__ __forceinline__ float artanh_clip(float x) {
    x = fminf(x, 1.0f - 1e-7f);
    return 0.5f * logf((1.0f + x) / (1.0f - x));
}

__device__ __forceinline__ ushort4 cvt4_bf16(float4 v) {
    ushort4 b;
    b.x = __bfloat16_as_ushort(__float2bfloat16(v.x));
    b.y = __bfloat16_as_ushort(__float2bfloat16(v.y));
    b.z = __bfloat16_as_ushort(__float2bfloat16(v.z));
    b.w = __bfloat16_as_ushort(__float2bfloat16(v.w));
    return b;
}

__device__ __forceinline__ void nt_store4(float4 v, float* p) {
    f32x4 w = {v.x, v.y, v.z, v.w};
    __builtin_nontemporal_store(w, (f32x4*)p);
}

// ---------------- K0: hyp_bias = proj(expmap0(bias)), plus b2 = ||hb||^2 ----
__global__ void k0_bias(const float* __restrict__ bias, float* __restrict__ hbg) {
    __shared__ float sp[4];
    __shared__ float s_g;
    int t = threadIdx.x;
    float u = bias[t];
    float v = u * u;
    #pragma unroll
    for (int o = 1; o < 64; o <<= 1) v += __shfl_xor(v, o);
    if ((t & 63) == 0) sp[t >> 6] = v;
    __syncthreads();
    if (t == 0) {
        float s  = sp[0] + sp[1] + sp[2] + sp[3];
        float un = fmaxf(sqrtf(s), 1e-15f);
        float t1 = tanhf(un);
        s_g = (t1 > 0.996f) ? (0.996f / un) : (t1 / un);
    }
    __syncthreads();
    float hb = s_g * u;
    hbg[t] = hb;
    float v2 = hb * hb;
    #pragma unroll
    for (int o = 1; o < 64; o <<= 1) v2 += __shfl_xor(v2, o);
    if ((t & 63) == 0) sp[t >> 6] = v2;
    __syncthreads();
    if (t == 0) hbg[256] = sp[0] + sp[1] + sp[2] + sp[3];
}

// ---------------- K1: HypLinear + logmap0 -> xtT (bf16, transposed [D][N]) --
// 16 rows/block, grid 512 (2 blocks/CU). x tile in LDS, read via same-address
// broadcasts (conflict-free); W staged in LDS 32-k chunks, coalesced.
__global__ __launch_bounds__(256) void k1_hyplinear(
    const float* __restrict__ x, const float* __restrict__ W,
    const float* __restrict__ hbg, __hip_bfloat16* __restrict__ xtT)
{
    __shared__ __align__(16) float sx[16][264];   // x tile; later reused for mx
    __shared__ __align__(16) float sw[256][36];   // W k-chunk [d][32]
    __shared__ float s_xn[16], s_P[16], s_Q[16];
    __shared__ float s_hb[256];
    __shared__ float s_b2;

    const int t  = threadIdx.x;
    const int r0 = blockIdx.x * 16;
    const int row = t >> 4;
    const int j16 = (t & 15) * 4;

    {   // stage x tile, coalesced (16 threads/row x 4 float4)
        #pragma unroll
        for (int i = 0; i < 4; i++)
            *(float4*)(&sx[row][j16 + 64 * i]) =
                *(const float4*)(x + (r0 + row) * 256 + j16 + 64 * i);
    }
    s_hb[t] = hbg[t];
    if (t == 0) s_b2 = hbg[256];
    __syncthreads();

    {   // per-row ||x||^2 (strided, <=2-way banks)
        int r = t >> 4, j = t & 15;
        float s2 = 0.f;
        #pragma unroll
        for (int i = 0; i < 16; i++) { float v = sx[r][j + 16 * i]; s2 += v * v; }
        s2 += __shfl_xor(s2, 1); s2 += __shfl_xor(s2, 2);
        s2 += __shfl_xor(s2, 4); s2 += __shfl_xor(s2, 8);
        if (j == 0) s_xn[r] = s2;
    }

    float acc[16];
    #pragma unroll
    for (int r = 0; r < 16; r++) acc[r] = 0.f;

    for (int kc = 0; kc < 8; kc++) {
        __syncthreads();
        {   // stage W chunk [256][32], coalesced
            int c4 = (t & 7) * 4;
            #pragma unroll
            for (int i = 0; i < 8; i++) {
                int d = i * 32 + (t >> 3);
                *(float4*)(&sw[d][c4]) = *(const float4*)(W + d * 256 + kc * 32 + c4);
            }
        }
        __syncthreads();
        #pragma unroll
        for (int kk = 0; kk < 8; kk++) {
            float4 w4 = *(const float4*)(&sw[t][kk * 4]);
            #pragma unroll
            for (int r = 0; r < 16; r++) {
                // same address across all threads -> LDS broadcast
                float4 x4 = *(const float4*)(&sx[r][kc * 32 + kk * 4]);
                acc[r] = fmaf(x4.x, w4.x, acc[r]);
                acc[r] = fmaf(x4.y, w4.y, acc[r]);
                acc[r] = fmaf(x4.z, w4.z, acc[r]);
                acc[r] = fmaf(x4.w, w4.w, acc[r]);
            }
        }
    }
    __syncthreads();
    #pragma unroll
    for (int r = 0; r < 16; r++) sx[r][t] = acc[r];   // reuse sx as mx tile
    __syncthreads();

    {   // per-row sumsq(mx), dot(mx, hb) -> scalar chain -> P, Q
        int r = t >> 4, j = t & 15;
        float s2 = 0.f, dt = 0.f;
        #pragma unroll
        for (int i = 0; i < 16; i++) {
            float v = sx[r][j + 16 * i];
            s2 += v * v;
            dt += v * s_hb[j + 16 * i];
        }
        s2 += __shfl_xor(s2, 1); s2 += __shfl_xor(s2, 2);
        s2 += __shfl_xor(s2, 4); s2 += __shfl_xor(s2, 8);
        dt += __shfl_xor(dt, 1); dt += __shfl_xor(dt, 2);
        dt += __shfl_xor(dt, 4); dt += __shfl_xor(dt, 8);
        if (j == 0) {
            float b2  = s_b2;
            float xn  = fmaxf(sqrtf(s_xn[r]), 1e-15f);
            float mx2 = s2;
            float mxn = fmaxf(sqrtf(mx2), 1e-15f);
            float at = artanh_clip(xn);
            float tt = tanhf(mxn / xn * at);
            float fr = tt / mxn;
            if (tt > 0.996f) fr = 0.996f / mxn;
            float mvn = fminf(tt, 0.996f);
            float x2  = mvn * mvn;
            float xy  = fr * dt;
            float cA  = 1.0f + 2.0f * xy + b2;
            float cB  = 1.0f - x2;
            float den = fmaxf(1.0f + 2.0f * xy + x2 * b2, 1e-15f);
            float P0 = cA * fr / den;
            float Q0 = cB / den;
            float hn = sqrtf(fmaxf(P0 * P0 * mx2 + 2.0f * P0 * Q0 * dt + Q0 * Q0 * b2, 0.0f));
            hn = fmaxf(hn, 1e-15f);
            float pf  = (hn > 0.996f) ? (0.996f / hn) : 1.0f;
            float hnp = fminf(hn, 0.996f);
            float lam = artanh_clip(hnp) / hnp;
            s_P[r] = lam * pf * P0;
            s_Q[r] = lam * pf * Q0;
        }
    }
    __syncthreads();

    {   // xt[r][t] = P[r]*mx[r][t] + Q[r]*hb[t]; write transposed xtT[t][r0+r]
        float hb = s_hb[t];
        unsigned int pk[8];
        #pragma unroll
        for (int r = 0; r < 16; r += 2) {
            float a0 = s_P[r]     * acc[r]     + s_Q[r]     * hb;
            float a1 = s_P[r + 1] * acc[r + 1] + s_Q[r + 1] * hb;
            unsigned int lo = (unsigned int)__bfloat16_as_ushort(__float2bfloat16(a0));
            unsigned int hi = (unsigned int)__bfloat16_as_ushort(__float2bfloat16(a1));
            pk[r >> 1] = lo | (hi << 16);
        }
        uint4* dst = (uint4*)(xtT + t * 8192 + r0);
        dst[0] = make_uint4(pk[0], pk[1], pk[2], pk[3]);
        dst[1] = make_uint4(pk[4], pk[5], pk[6], pk[7]);
    }
}

// ---------------- K2: split-N fused adj-copy + (adj @ xt) MFMA --------------
// grid 1024 (4 blocks/CU, whole grid resident). Block -> (m, c):
//   m = (bx>>5)*8 + (bx&7), c = (bx>>3)&3   [the 4 c-blocks of an m share an
//   XCD via bx%8 round-robin -> adj re-reads hit the shared per-XCD L2].
// BM=32, BN=64, BK=64, full K per block -> disjoint output, NO atomics/reduce.
// Wave (wrh, wc): wrh = row half (16 rows), wc = col fragment (16 cols);
// each wave runs the FULL K for its 16x16 block (2 MFMAs per BK=64 step).
__global__ __launch_bounds__(512) void k2_agg(
    const float* __restrict__ adj,
    const __hip_bfloat16* __restrict__ xtT,
    float* __restrict__ out_h,
    float* __restrict__ out_adj)
{
    __shared__ __align__(16) __hip_bfloat16 As[2][32][72];

    const int t    = threadIdx.x;
    const int lane = t & 63;
    const int wave = t >> 6;
    const int wrh  = wave >> 2;    // row half within BM=32
    const int wc   = wave & 3;     // 16-col fragment within BN=64
    const int bx   = blockIdx.x;
    const int m    = (bx >> 5) * 8 + (bx & 7);
    const int c    = (bx >> 3) & 3;
    const int m0   = m * 32;
    const int n0   = c * 64;

    const int srow = t >> 4;
    const int scol = (t & 15) * 4;
    const float* astage = adj     + (m0 + srow) * 8192 + scol;
    float*       ostage = out_adj + (m0 + srow) * 8192 + scol;

    const int arow = lane & 15;
    const int g8   = 8 * (lane >> 4);   // k-offset within a 32-k sub-step
    const __hip_bfloat16* bptr = xtT + (n0 + wc * 16 + arow) * 8192 + g8;

    f32x4 acc = (f32x4){0.f, 0.f, 0.f, 0.f};

    {   // prologue: stage tile 0 + nt adj passthrough
        float4 v = *(const float4*)(astage);
        nt_store4(v, ostage);
        *(ushort4*)(&As[0][srow][scol]) = cvt4_bf16(v);
    }
    __syncthreads();

    for (int kt = 0; kt < 128; kt++) {
        const int cur = kt & 1;
        const bool hn = (kt + 1 < 128);
        float4 v;
        if (hn) v = *(const float4*)(astage + (kt + 1) * 64);   // issue early

        short8v b0 = *(const short8v*)(bptr + kt * 64);
        short8v b1 = *(const short8v*)(bptr + kt * 64 + 32);
        short8v a0 = *(const short8v*)(&As[cur][wrh * 16 + arow][g8]);
        short8v a1 = *(const short8v*)(&As[cur][wrh * 16 + arow][32 + g8]);

        acc = __builtin_amdgcn_mfma_f32_16x16x32_bf16(a0, b0, acc, 0, 0, 0);
        acc = __builtin_amdgcn_mfma_f32_16x16x32_bf16(a1, b1, acc, 0, 0, 0);

        if (hn) {   // write-late: nt passthrough + next LDS buffer
            nt_store4(v, ostage + (kt + 1) * 64);
            *(ushort4*)(&As[cur ^ 1][srow][scol]) = cvt4_bf16(v);
        }
        __syncthreads();
    }

    // store support (disjoint 16x16 region per wave;
    // C layout: col=lane&15, row=(lane>>4)*4+q)
    const int crow0 = 4 * (lane >> 4);
    const int ccol  = lane & 15;
    #pragma unroll
    for (int q = 0; q < 4; q++)
        out_h[(m0 + wrh * 16 + crow0 + q) * 256 + n0 + wc * 16 + ccol] = acc[q];
}

// ---------------- K3: in-place epilogue on support (out_h) -------------------
__global__ __launch_bounds__(256) void k3_epilogue(float* __restrict__ h) {
    const int t = threadIdx.x;
    const int r = blockIdx.x * 16 + (t >> 4);
    const int j = t & 15;
    float* p = h + r * 256 + j * 16;

    float4 v[4];
    float s2 = 0.f, sp = 0.f;
    #pragma unroll
    for (int i = 0; i < 4; i++) {
        v[i] = *(const float4*)(p + 4 * i);
        s2 += v[i].x * v[i].x + v[i].y * v[i].y + v[i].z * v[i].z + v[i].w * v[i].w;
        float px = fmaxf(v[i].x, 0.f), py = fmaxf(v[i].y, 0.f);
        float pz = fmaxf(v[i].z, 0.f), pw = fmaxf(v[i].w, 0.f);
        sp += px * px + py * py + pz * pz + pw * pw;
    }
    s2 += __shfl_xor(s2, 1); s2 += __shfl_xor(s2, 2); s2 += __shfl_xor(s2, 4); s2 += __shfl_xor(s2, 8);
    sp += __shfl_xor(sp, 1); sp += __shfl_xor(sp, 2); sp += __shfl_xor(sp, 4); sp += __shfl_xor(sp, 8);

    float ns = fmaxf(sqrtf(s2), 1e-15f);
    float t1 = tanhf(ns);
    float alpha = (t1 > 0.996f) ? (0.996f / ns) : (t1 / ns);   // expmap0+proj
    float nh = fminf(t1, 0.996f);
    float beta = artanh_clip(nh) / nh;                          // logmap0
    float ba = beta * alpha;
    float nxt = fmaxf(ba * sqrtf(sp), 1e-15f);                  // ||relu(xt)||
    float t2 = tanhf(nxt);
    float delta = (t2 > 0.996f) ? (0.996f / nxt) : (t2 / nxt);  // expmap0+proj
    float F = delta * ba;

    #pragma unroll
    for (int i = 0; i < 4; i++) {
        float4 o;
        o.x = F * fmaxf(v[i].x, 0.f);
        o.y = F * fmaxf(v[i].y, 0.f);
        o.z = F * fmaxf(v[i].z, 0.f);
        o.w = F * fmaxf(v[i].w, 0.f);
        *(float4*)(p + 4 * i) = o;
    }
}

extern "C" void kernel_launch(void* const* d_in, const int* in_sizes, int n_in,
                              void* d_out, int out_size, void* d_ws, size_t ws_size,
                              hipStream_t stream)
{
    const float* x    = (const float*)d_in[0];
    const float* adj  = (const float*)d_in[1];
    const float* W    = (const float*)d_in[2];
    const float* bias = (const float*)d_in[3];

    float* out_h   = (float*)d_out;
    float* out_adj = out_h + (size_t)N_NODES * D_DIM;

    __hip_bfloat16* xtT = (__hip_bfloat16*)d_ws;                       // [256][8192] bf16 = 4 MB
    float* hbg = (float*)((char*)d_ws + (size_t)D_DIM * N_NODES * 2);  // hb[256] + b2

    k0_bias<<<1, 256, 0, stream>>>(bias, hbg);
    k1_hyplinear<<<512, 256, 0, stream>>>(x, W, hbg, xtT);
    k2_agg<<<1024, 512, 0, stream>>>(adj, xtT, out_h, out_adj);
    k3_epilogue<<<512, 256, 0, stream>>>(out_h);
}

// Round 7
// 378.073 us; speedup vs baseline: 1.3817x; 1.3817x over previous
//
#include <hip/hip_runtime.h>
#include <hip/hip_bf16.h>

#define N_NODES 8192
#define D_DIM   256

typedef __attribute__((ext_vector_type(8))) short short8v;   // 8 x bf16 (4 VGPR)
typedef __attribute__((ext_vector_type(4))) float f32x4;

__device__ __forceinline__ float artanh_clip(float x) {
    x = fminf(x, 1.0f - 1e-7f);
    return 0.5f * logf((1.0f + x) / (1.0f - x));
}

__device__ __forceinline__ ushort4 cvt4_bf16(float4 v) {
    ushort4 b;
    b.x = __bfloat16_as_ushort(__float2bfloat16(v.x));
    b.y = __bfloat16_as_ushort(__float2bfloat16(v.y));
    b.z = __bfloat16_as_ushort(__float2bfloat16(v.z));
    b.w = __bfloat16_as_ushort(__float2bfloat16(v.w));
    return b;
}

__device__ __forceinline__ void nt_store4(float4 v, float* p) {
    f32x4 w = {v.x, v.y, v.z, v.w};
    __builtin_nontemporal_store(w, (f32x4*)p);
}

// ---------------- K0: hyp_bias = proj(expmap0(bias)), plus b2 = ||hb||^2 ----
__global__ void k0_bias(const float* __restrict__ bias, float* __restrict__ hbg) {
    __shared__ float sp[4];
    __shared__ float s_g;
    int t = threadIdx.x;
    float u = bias[t];
    float v = u * u;
    #pragma unroll
    for (int o = 1; o < 64; o <<= 1) v += __shfl_xor(v, o);
    if ((t & 63) == 0) sp[t >> 6] = v;
    __syncthreads();
    if (t == 0) {
        float s  = sp[0] + sp[1] + sp[2] + sp[3];
        float un = fmaxf(sqrtf(s), 1e-15f);
        float t1 = tanhf(un);
        s_g = (t1 > 0.996f) ? (0.996f / un) : (t1 / un);
    }
    __syncthreads();
    float hb = s_g * u;
    hbg[t] = hb;
    float v2 = hb * hb;
    #pragma unroll
    for (int o = 1; o < 64; o <<= 1) v2 += __shfl_xor(v2, o);
    if ((t & 63) == 0) sp[t >> 6] = v2;
    __syncthreads();
    if (t == 0) hbg[256] = sp[0] + sp[1] + sp[2] + sp[3];
}

// ---------------- K1: HypLinear + logmap0 -> xtT (bf16, transposed [D][N]) --
// 16 rows/block, grid 512 (2 blocks/CU). x tile in LDS, read via same-address
// broadcasts (conflict-free); W staged in LDS 32-k chunks, coalesced.
__global__ __launch_bounds__(256) void k1_hyplinear(
    const float* __restrict__ x, const float* __restrict__ W,
    const float* __restrict__ hbg, __hip_bfloat16* __restrict__ xtT)
{
    __shared__ __align__(16) float sx[16][264];   // x tile; later reused for mx
    __shared__ __align__(16) float sw[256][36];   // W k-chunk [d][32]
    __shared__ float s_xn[16], s_P[16], s_Q[16];
    __shared__ float s_hb[256];
    __shared__ float s_b2;

    const int t  = threadIdx.x;
    const int r0 = blockIdx.x * 16;
    const int row = t >> 4;
    const int j16 = (t & 15) * 4;

    {   // stage x tile, coalesced (16 threads/row x 4 float4)
        #pragma unroll
        for (int i = 0; i < 4; i++)
            *(float4*)(&sx[row][j16 + 64 * i]) =
                *(const float4*)(x + (r0 + row) * 256 + j16 + 64 * i);
    }
    s_hb[t] = hbg[t];
    if (t == 0) s_b2 = hbg[256];
    __syncthreads();

    {   // per-row ||x||^2 (strided, <=2-way banks)
        int r = t >> 4, j = t & 15;
        float s2 = 0.f;
        #pragma unroll
        for (int i = 0; i < 16; i++) { float v = sx[r][j + 16 * i]; s2 += v * v; }
        s2 += __shfl_xor(s2, 1); s2 += __shfl_xor(s2, 2);
        s2 += __shfl_xor(s2, 4); s2 += __shfl_xor(s2, 8);
        if (j == 0) s_xn[r] = s2;
    }

    float acc[16];
    #pragma unroll
    for (int r = 0; r < 16; r++) acc[r] = 0.f;

    for (int kc = 0; kc < 8; kc++) {
        __syncthreads();
        {   // stage W chunk [256][32], coalesced
            int c4 = (t & 7) * 4;
            #pragma unroll
            for (int i = 0; i < 8; i++) {
                int d = i * 32 + (t >> 3);
                *(float4*)(&sw[d][c4]) = *(const float4*)(W + d * 256 + kc * 32 + c4);
            }
        }
        __syncthreads();
        #pragma unroll
        for (int kk = 0; kk < 8; kk++) {
            float4 w4 = *(const float4*)(&sw[t][kk * 4]);
            #pragma unroll
            for (int r = 0; r < 16; r++) {
                // same address across all threads -> LDS broadcast
                float4 x4 = *(const float4*)(&sx[r][kc * 32 + kk * 4]);
                acc[r] = fmaf(x4.x, w4.x, acc[r]);
                acc[r] = fmaf(x4.y, w4.y, acc[r]);
                acc[r] = fmaf(x4.z, w4.z, acc[r]);
                acc[r] = fmaf(x4.w, w4.w, acc[r]);
            }
        }
    }
    __syncthreads();
    #pragma unroll
    for (int r = 0; r < 16; r++) sx[r][t] = acc[r];   // reuse sx as mx tile
    __syncthreads();

    {   // per-row sumsq(mx), dot(mx, hb) -> scalar chain -> P, Q
        int r = t >> 4, j = t & 15;
        float s2 = 0.f, dt = 0.f;
        #pragma unroll
        for (int i = 0; i < 16; i++) {
            float v = sx[r][j + 16 * i];
            s2 += v * v;
            dt += v * s_hb[j + 16 * i];
        }
        s2 += __shfl_xor(s2, 1); s2 += __shfl_xor(s2, 2);
        s2 += __shfl_xor(s2, 4); s2 += __shfl_xor(s2, 8);
        dt += __shfl_xor(dt, 1); dt += __shfl_xor(dt, 2);
        dt += __shfl_xor(dt, 4); dt += __shfl_xor(dt, 8);
        if (j == 0) {
            float b2  = s_b2;
            float xn  = fmaxf(sqrtf(s_xn[r]), 1e-15f);
            float mx2 = s2;
            float mxn = fmaxf(sqrtf(mx2), 1e-15f);
            float at = artanh_clip(xn);
            float tt = tanhf(mxn / xn * at);
            float fr = tt / mxn;
            if (tt > 0.996f) fr = 0.996f / mxn;
            float mvn = fminf(tt, 0.996f);
            float x2  = mvn * mvn;
            float xy  = fr * dt;
            float cA  = 1.0f + 2.0f * xy + b2;
            float cB  = 1.0f - x2;
            float den = fmaxf(1.0f + 2.0f * xy + x2 * b2, 1e-15f);
            float P0 = cA * fr / den;
            float Q0 = cB / den;
            float hn = sqrtf(fmaxf(P0 * P0 * mx2 + 2.0f * P0 * Q0 * dt + Q0 * Q0 * b2, 0.0f));
            hn = fmaxf(hn, 1e-15f);
            float pf  = (hn > 0.996f) ? (0.996f / hn) : 1.0f;
            float hnp = fminf(hn, 0.996f);
            float lam = artanh_clip(hnp) / hnp;
            s_P[r] = lam * pf * P0;
            s_Q[r] = lam * pf * Q0;
        }
    }
    __syncthreads();

    {   // xt[r][t] = P[r]*mx[r][t] + Q[r]*hb[t]; write transposed xtT[t][r0+r]
        float hb = s_hb[t];
        unsigned int pk[8];
        #pragma unroll
        for (int r = 0; r < 16; r += 2) {
            float a0 = s_P[r]     * acc[r]     + s_Q[r]     * hb;
            float a1 = s_P[r + 1] * acc[r + 1] + s_Q[r + 1] * hb;
            unsigned int lo = (unsigned int)__bfloat16_as_ushort(__float2bfloat16(a0));
            unsigned int hi = (unsigned int)__bfloat16_as_ushort(__float2bfloat16(a1));
            pk[r >> 1] = lo | (hi << 16);
        }
        uint4* dst = (uint4*)(xtT + t * 8192 + r0);
        dst[0] = make_uint4(pk[0], pk[1], pk[2], pk[3]);
        dst[1] = make_uint4(pk[4], pk[5], pk[6], pk[7]);
    }
}

// ---------------- K2: fused adj-copy + (adj @ xt) MFMA, BM=16 x BN=256 ------
// grid 512 (2 blocks/CU). BM=16 rows, BN=256 (full width -> adj read ONCE,
// written ONCE; disjoint outputs, no atomics). 4 waves = 4 n-quarters,
// 8 MFMA/iter/wave. 2-iteration register pipeline: A-tile for kt+2 is loaded
// at iter kt, cvt+LDS-written at iter kt+1, consumed at iter kt+2 -> a full
// iteration of HBM latency hiding. B read direct from L2-resident xtT, issued
// FIRST each iter so its vmcnt wait doesn't drain the A prefetch.
__global__ __launch_bounds__(256) void k2_agg(
    const float* __restrict__ adj,
    const __hip_bfloat16* __restrict__ xtT,
    float* __restrict__ out_h,
    float* __restrict__ out_adj)
{
    __shared__ __align__(16) __hip_bfloat16 As[2][16][72];  // 144 B row stride

    const int t    = threadIdx.x;
    const int lane = t & 63;
    const int wave = t >> 6;        // n-quarter (64 cols of out)
    const int m0   = blockIdx.x * 16;

    // staging: thread t handles row srow, 16B f32 slot sslot
    const int srow  = t >> 4;
    const int sslot = t & 15;
    const float* aptr = adj     + (m0 + srow) * 8192 + sslot * 4;
    float*       optr = out_adj + (m0 + srow) * 8192 + sslot * 4;

    // fragment indices
    const int arow = lane & 15;
    const int g8   = 8 * (lane >> 4);
    const __hip_bfloat16* bbase = xtT + (wave * 64 + arow) * 8192 + g8;

    f32x4 acc[4];
    #pragma unroll
    for (int i = 0; i < 4; i++) acc[i] = (f32x4){0.f, 0.f, 0.f, 0.f};

    float4 Ta, Tb;
    Ta = *(const float4*)(aptr);            // tile 0
    Tb = *(const float4*)(aptr + 64);       // tile 1
    nt_store4(Ta, optr);                    // passthrough tile 0
    *(ushort4*)(&As[0][srow][sslot * 4]) = cvt4_bf16(Ta);
    __syncthreads();

    for (int kt = 0; kt < 128; kt += 2) {
        {   // ---- even: consume buf0 (tile kt); Tb holds tile kt+1
            short8v B[4][2];
            #pragma unroll
            for (int nf = 0; nf < 4; nf++)
                #pragma unroll
                for (int ks = 0; ks < 2; ks++)
                    B[nf][ks] = *(const short8v*)(bbase + nf * 16 * 8192 + kt * 64 + ks * 32);
            if (kt + 2 < 128) Ta = *(const float4*)(aptr + (kt + 2) * 64);

            short8v a0 = *(const short8v*)(&As[0][arow][g8]);
            short8v a1 = *(const short8v*)(&As[0][arow][32 + g8]);
            #pragma unroll
            for (int nf = 0; nf < 4; nf++) {
                acc[nf] = __builtin_amdgcn_mfma_f32_16x16x32_bf16(a0, B[nf][0], acc[nf], 0, 0, 0);
                acc[nf] = __builtin_amdgcn_mfma_f32_16x16x32_bf16(a1, B[nf][1], acc[nf], 0, 0, 0);
            }
            // tile kt+1: passthrough + LDS buf1
            nt_store4(Tb, optr + (kt + 1) * 64);
            *(ushort4*)(&As[1][srow][sslot * 4]) = cvt4_bf16(Tb);
            __syncthreads();
        }
        {   // ---- odd: consume buf1 (tile kt+1); Ta holds tile kt+2
            short8v B[4][2];
            #pragma unroll
            for (int nf = 0; nf < 4; nf++)
                #pragma unroll
                for (int ks = 0; ks < 2; ks++)
                    B[nf][ks] = *(const short8v*)(bbase + nf * 16 * 8192 + (kt + 1) * 64 + ks * 32);
            if (kt + 3 < 128) Tb = *(const float4*)(aptr + (kt + 3) * 64);

            short8v a0 = *(const short8v*)(&As[1][arow][g8]);
            short8v a1 = *(const short8v*)(&As[1][arow][32 + g8]);
            #pragma unroll
            for (int nf = 0; nf < 4; nf++) {
                acc[nf] = __builtin_amdgcn_mfma_f32_16x16x32_bf16(a0, B[nf][0], acc[nf], 0, 0, 0);
                acc[nf] = __builtin_amdgcn_mfma_f32_16x16x32_bf16(a1, B[nf][1], acc[nf], 0, 0, 0);
            }
            if (kt + 2 < 128) {   // tile kt+2: passthrough + LDS buf0
                nt_store4(Ta, optr + (kt + 2) * 64);
                *(ushort4*)(&As[0][srow][sslot * 4]) = cvt4_bf16(Ta);
            }
            __syncthreads();
        }
    }

    // store support (disjoint; C layout: col=lane&15, row=(lane>>4)*4+q)
    const int crow0 = 4 * (lane >> 4);
    const int ccol  = lane & 15;
    #pragma unroll
    for (int nf = 0; nf < 4; nf++)
        #pragma unroll
        for (int q = 0; q < 4; q++)
            out_h[(m0 + crow0 + q) * 256 + wave * 64 + nf * 16 + ccol] = acc[nf][q];
}

// ---------------- K3: in-place epilogue on support (out_h) -------------------
__global__ __launch_bounds__(256) void k3_epilogue(float* __restrict__ h) {
    const int t = threadIdx.x;
    const int r = blockIdx.x * 16 + (t >> 4);
    const int j = t & 15;
    float* p = h + r * 256 + j * 16;

    float4 v[4];
    float s2 = 0.f, sp = 0.f;
    #pragma unroll
    for (int i = 0; i < 4; i++) {
        v[i] = *(const float4*)(p + 4 * i);
        s2 += v[i].x * v[i].x + v[i].y * v[i].y + v[i].z * v[i].z + v[i].w * v[i].w;
        float px = fmaxf(v[i].x, 0.f), py = fmaxf(v[i].y, 0.f);
        float pz = fmaxf(v[i].z, 0.f), pw = fmaxf(v[i].w, 0.f);
        sp += px * px + py * py + pz * pz + pw * pw;
    }
    s2 += __shfl_xor(s2, 1); s2 += __shfl_xor(s2, 2); s2 += __shfl_xor(s2, 4); s2 += __shfl_xor(s2, 8);
    sp += __shfl_xor(sp, 1); sp += __shfl_xor(sp, 2); sp += __shfl_xor(sp, 4); sp += __shfl_xor(sp, 8);

    float ns = fmaxf(sqrtf(s2), 1e-15f);
    float t1 = tanhf(ns);
    float alpha = (t1 > 0.996f) ? (0.996f / ns) : (t1 / ns);   // expmap0+proj
    float nh = fminf(t1, 0.996f);
    float beta = artanh_clip(nh) / nh;                          // logmap0
    float ba = beta * alpha;
    float nxt = fmaxf(ba * sqrtf(sp), 1e-15f);                  // ||relu(xt)||
    float t2 = tanhf(nxt);
    float delta = (t2 > 0.996f) ? (0.996f / nxt) : (t2 / nxt);  // expmap0+proj
    float F = delta * ba;

    #pragma unroll
    for (int i = 0; i < 4; i++) {
        float4 o;
        o.x = F * fmaxf(v[i].x, 0.f);
        o.y = F * fmaxf(v[i].y, 0.f);
        o.z = F * fmaxf(v[i].z, 0.f);
        o.w = F * fmaxf(v[i].w, 0.f);
        *(float4*)(p + 4 * i) = o;
    }
}

extern "C" void kernel_launch(void* const* d_in, const int* in_sizes, int n_in,
                              void* d_out, int out_size, void* d_ws, size_t ws_size,
                              hipStream_t stream)
{
    const float* x    = (const float*)d_in[0];
    const float* adj  = (const float*)d_in[1];
    const float* W    = (const float*)d_in[2];
    const float* bias = (const float*)d_in[3];

    float* out_h   = (float*)d_out;
    float* out_adj = out_h + (size_t)N_NODES * D_DIM;

    __hip_bfloat16* xtT = (__hip_bfloat16*)d_ws;                       // [256][8192] bf16 = 4 MB
    float* hbg = (float*)((char*)d_ws + (size_t)D_DIM * N_NODES * 2);  // hb[256] + b2

    k0_bias<<<1, 256, 0, stream>>>(bias, hbg);
    k1_hyplinear<<<512, 256, 0, stream>>>(x, W, hbg, xtT);
    k2_agg<<<512, 256, 0, stream>>>(adj, xtT, out_h, out_adj);
    k3_epilogue<<<512, 256, 0, stream>>>(out_h);
}